// Round 3
// baseline (37962.766 us; speedup 1.0000x reference)
//
#include <hip/hip_runtime.h>
#include <stdint.h>

#define N_NEUR  1024
#define N_INP   256
#define N_OUTC  32
#define T_STEPS 500
#define BATCH   64
#define N_DEL   8
#define NB      (N_NEUR*BATCH)     // 65536 (n,b) elements, b fastest
#define HSLOTS  132                // circular history depth (max delay 128 + margin)
#define NPART   16                 // split-K partials per element (after in-block reduce)

// ---------------------------------------------------------------------------
// W_eff[d][e][o] = dmap[d][e][o] * sign[e] * |w[e][o]|
__global__ __launch_bounds__(256) void prep_w(const float* __restrict__ w,
                                              const float* __restrict__ signs,
                                              const float* __restrict__ dmap,
                                              float* __restrict__ W) {
    size_t i = (size_t)blockIdx.x * 256 + threadIdx.x;   // < 8*1024*1024
    int r = (int)(i & (size_t)(N_NEUR * N_NEUR - 1));    // (e,o) flat
    int e = r >> 10;
    W[i] = dmap[i] * signs[e] * fabsf(w[r]);
}

// ---------------------------------------------------------------------------
// inpT[t][c][b] = inputs[b][t][c]   (LDS-tiled transpose, both sides coalesced)
__global__ __launch_bounds__(256) void transpose_inp(const float* __restrict__ inp,
                                                     float* __restrict__ inpT) {
    __shared__ float L[N_INP * 64];          // [c][b], XOR-swizzled
    int t = blockIdx.x;
    int tid = threadIdx.x;                   // = c on the read side
    for (int b = 0; b < 64; ++b) {
        float v = inp[((size_t)b * T_STEPS + t) * N_INP + tid];  // coalesced over c
        L[tid * 64 + (b ^ (tid & 63))] = v;
    }
    __syncthreads();
    int lane = tid & 63;
    int wv   = tid >> 6;
    for (int cc = 0; cc < 64; ++cc) {
        int c = cc * 4 + wv;
        inpT[((size_t)t * N_INP + c) * 64 + lane] = L[c * 64 + (lane ^ (c & 63))];
    }
}

// ---------------------------------------------------------------------------
// Pointwise update of step s, one wave: n in [n0, n0+4), lanes = batch.
// Computes h1 on the fly, reduces NPART split-K partials, updates mem/w_p,
// writes hist circular slot and packed spike bits.
__device__ __forceinline__ void pointwise_wave(int s, int n0, int lane,
        const float* __restrict__ part, const float* __restrict__ inpT,
        const float* __restrict__ w_in, const float* __restrict__ p,
        float* __restrict__ mem, float* __restrict__ wp_arr,
        float* __restrict__ histc, unsigned long long* __restrict__ spk) {
    float h1v[4] = {0.f, 0.f, 0.f, 0.f};
    const float* irow = inpT + (size_t)s * (N_INP * 64) + lane;
    const float4* wcol = (const float4*)(w_in + n0);   // uniform -> s_load_dwordx4
#pragma unroll 4
    for (int c = 0; c < N_INP; ++c) {
        float a = irow[(size_t)c * 64];                // coalesced vload
        float4 wq = wcol[(size_t)c * (N_NEUR / 4)];
        h1v[0] = fmaf(a, wq.x, h1v[0]);
        h1v[1] = fmaf(a, wq.y, h1v[1]);
        h1v[2] = fmaf(a, wq.z, h1v[2]);
        h1v[3] = fmaf(a, wq.w, h1v[3]);
    }
    int slot = s % HSLOTS;
#pragma unroll
    for (int r = 0; r < 4; ++r) {
        int n = n0 + r;
        int i = n * 64 + lane;
        float syn = 0.f;
#pragma unroll
        for (int kc = 0; kc < NPART; ++kc) syn += part[(size_t)kc * NB + i];
        float m = mem[i];
        float w = wp_arr[i];
        float out = (m - 1.0f > 0.0f) ? 1.0f : 0.0f;
        float pn = p[n];
        float pd = (pn < 0.0f) ? 1.0f : 0.0f;
        w = w * 0.95f + out * pn * (1.0f + pd * w);
        wp_arr[i] = w;
        histc[(size_t)slot * NB + i] = out * (1.0f + w);   // >0 iff spike
        mem[i] = 0.9f * m + h1v[r] + syn - out;
        unsigned long long mask = __ballot(out > 0.0f);
        if (lane == 0) spk[(size_t)s * N_NEUR + n] = mask;
    }
}

// ---------------------------------------------------------------------------
// One simulation step, single launch, grid = 1088 blocks x 256:
//  - blocks [0,1024): split-K GEMM. Block = (ot, kcg); its 4 waves take
//    kc = kcg*4+wv (64 k-chunks: d = kc&7, e-range 128), LDS-reduce 4->1,
//    write partial[kcg][n][b].
//      syn_p[b][o] = sum_d sum_e hist[slot(t-1-delay_d)][e][b] * W[d][e][o]
//  - blocks [1024,1088): pointwise update of step t-1 (writes hist slot
//    (t-1)%HSLOTS, mem, w_p, spk -- nothing step-t's GEMM reads: min delay=1
//    means the GEMM reads slots <= t-2).
__global__ __launch_bounds__(256) void fused_step(int t,
        const float* __restrict__ W, const int* __restrict__ delays,
        const float* __restrict__ inpT, const float* __restrict__ w_in,
        const float* __restrict__ p,
        float* __restrict__ histc, float* __restrict__ mem,
        float* __restrict__ wp_arr, unsigned long long* __restrict__ spk,
        float* __restrict__ part_w, const float* __restrict__ part_r) {
    __shared__ float R[4 * 16 * 64];   // 16 KB reduce buffer
    int bx = blockIdx.x;
    int tid = threadIdx.x;
    int lane = tid & 63;
    int wv   = tid >> 6;
    if (bx >= 1024) {
        if (t > 0) {
            int pb = bx - 1024;                          // [0,64)
            pointwise_wave(t - 1, pb * 16 + wv * 4, lane, part_r, inpT, w_in,
                           p, mem, wp_arr, histc, spk);
        }
        return;
    }
    int ot  = bx & 63;                 // o-tile of 16
    int kcg = bx >> 6;                 // [0,16) partial group
    int kc  = kcg * 4 + wv;            // [0,64) k-chunk
    int d   = kc & 7;
    int e0  = (kc >> 3) << 7;          // e-chunk of 128
    int dl  = delays[d];
    int tau = t - 1 - dl;
    int slot = ((tau % HSLOTS) + HSLOTS) % HSLOTS;   // negative tau -> zero slot
    const float* hrow  = histc + (size_t)slot * NB + (size_t)e0 * 64 + lane;
    const float* wbase = W + ((size_t)d * N_NEUR + e0) * N_NEUR + ot * 16;
    float acc[16];
#pragma unroll
    for (int j = 0; j < 16; ++j) acc[j] = 0.f;
#pragma unroll 4
    for (int e = 0; e < 128; ++e) {
        float a = hrow[(size_t)e * 64];                 // coalesced vload
        const float4* wr = (const float4*)(wbase + (size_t)e * N_NEUR);  // uniform
        float4 w0 = wr[0], w1 = wr[1], w2 = wr[2], w3 = wr[3];
        acc[0]  = fmaf(a, w0.x, acc[0]);  acc[1]  = fmaf(a, w0.y, acc[1]);
        acc[2]  = fmaf(a, w0.z, acc[2]);  acc[3]  = fmaf(a, w0.w, acc[3]);
        acc[4]  = fmaf(a, w1.x, acc[4]);  acc[5]  = fmaf(a, w1.y, acc[5]);
        acc[6]  = fmaf(a, w1.z, acc[6]);  acc[7]  = fmaf(a, w1.w, acc[7]);
        acc[8]  = fmaf(a, w2.x, acc[8]);  acc[9]  = fmaf(a, w2.y, acc[9]);
        acc[10] = fmaf(a, w2.z, acc[10]); acc[11] = fmaf(a, w2.w, acc[11]);
        acc[12] = fmaf(a, w3.x, acc[12]); acc[13] = fmaf(a, w3.y, acc[13]);
        acc[14] = fmaf(a, w3.z, acc[14]); acc[15] = fmaf(a, w3.w, acc[15]);
    }
    // reduce the 4 waves' accumulators (4 k-chunks) -> one partial per block
    float* Rw = R + (size_t)(wv * 16) * 64 + lane;
#pragma unroll
    for (int j = 0; j < 16; ++j) Rw[(size_t)j * 64] = acc[j];
    __syncthreads();
#pragma unroll
    for (int r = 0; r < 4; ++r) {
        int j = wv + r * 4;            // 4 waves cover 16 j's
        float s = R[(size_t)(0 * 16 + j) * 64 + lane]
                + R[(size_t)(1 * 16 + j) * 64 + lane]
                + R[(size_t)(2 * 16 + j) * 64 + lane]
                + R[(size_t)(3 * 16 + j) * 64 + lane];
        part_w[(size_t)kcg * NB + (size_t)(ot * 16 + j) * 64 + lane] = s;
    }
}

// ---------------------------------------------------------------------------
__global__ __launch_bounds__(256) void tail_pointwise(
        const float* __restrict__ part, const float* __restrict__ inpT,
        const float* __restrict__ w_in, const float* __restrict__ p,
        float* __restrict__ mem, float* __restrict__ wp_arr,
        float* __restrict__ histc, unsigned long long* __restrict__ spk) {
    int lane = threadIdx.x & 63;
    int wv   = threadIdx.x >> 6;
    pointwise_wave(T_STEPS - 1, blockIdx.x * 16 + wv * 4, lane, part, inpT,
                   w_in, p, mem, wp_arr, histc, spk);
}

// ---------------------------------------------------------------------------
// h2[t][b][o] = sum_n spk_bit(t,n,b) * w_out[n][o]
__global__ __launch_bounds__(256) void h2_gemm(const unsigned long long* __restrict__ spk,
                                               const float* __restrict__ w_out,
                                               float* __restrict__ h2) {
    int t = blockIdx.x;
    int lane = threadIdx.x & 63;     // = b
    int wv   = threadIdx.x >> 6;
    int o0 = wv * 8;
    float acc[8];
#pragma unroll
    for (int j = 0; j < 8; ++j) acc[j] = 0.f;
    for (int n = 0; n < N_NEUR; ++n) {
        unsigned long long mask = spk[(size_t)t * N_NEUR + n];   // uniform
        float s = (float)((mask >> lane) & 1ULL);
        const float* wr = w_out + n * N_OUTC + o0;               // uniform
#pragma unroll
        for (int j = 0; j < 8; ++j) acc[j] = fmaf(s, wr[j], acc[j]);
    }
#pragma unroll
    for (int j = 0; j < 8; ++j)
        h2[((size_t)t * BATCH + lane) * N_OUTC + o0 + j] = acc[j];
}

// ---------------------------------------------------------------------------
// out[b][t][o] : leaky-integrator scan over h2
__global__ __launch_bounds__(256) void out_scan(const float* __restrict__ h2,
                                                float* __restrict__ out) {
    int tid = blockIdx.x * 256 + threadIdx.x;   // 2048 = 64b * 32o
    int o = tid & 31;
    int b = tid >> 5;
    float acc = 0.f;
    for (int t = 0; t < T_STEPS; ++t) {
        acc = 0.9f * acc + h2[((size_t)t * BATCH + b) * N_OUTC + o];
        out[((size_t)b * T_STEPS + t) * N_OUTC + o] = acc;
    }
}

// ---------------------------------------------------------------------------
extern "C" void kernel_launch(void* const* d_in, const int* in_sizes, int n_in,
                              void* d_out, int out_size, void* d_ws, size_t ws_size,
                              hipStream_t stream) {
    (void)in_sizes; (void)n_in; (void)out_size; (void)ws_size;
    const float* inputs = (const float*)d_in[0];
    const float* w      = (const float*)d_in[1];
    const float* w_in   = (const float*)d_in[2];
    const float* w_out  = (const float*)d_in[3];
    const float* signs  = (const float*)d_in[4];
    const float* p      = (const float*)d_in[5];
    const float* dmap   = (const float*)d_in[6];
    const int*   delays = (const int*)d_in[7];
    float* out = (float*)d_out;

    // workspace layout (~109 MiB total, under the proven 120.6 MiB budget)
    float* ws    = (float*)d_ws;
    float* W     = ws;                                        //  8,388,608 f
    float* inpT  = W + (size_t)N_DEL * N_NEUR * N_NEUR;       //  8,192,000 f
    float* histc = inpT + (size_t)T_STEPS * N_INP * BATCH;    //  8,650,752 f
    float* part0 = histc + (size_t)HSLOTS * NB;               //  1,048,576 f
    float* part1 = part0 + (size_t)NPART * NB;                //  1,048,576 f
    float* mem   = part1 + (size_t)NPART * NB;                //     65,536 f
    float* wp    = mem + NB;                                  //     65,536 f
    float* h2    = wp + NB;                                   //  1,024,000 f
    unsigned long long* spk = (unsigned long long*)(h2 + (size_t)T_STEPS * BATCH * N_OUTC);

    // zero-init: circular history (wrapped reads must see 0), mem+wp (adjacent)
    hipMemsetAsync(histc, 0, (size_t)HSLOTS * NB * sizeof(float), stream);
    hipMemsetAsync(mem, 0, (size_t)2 * NB * sizeof(float), stream);

    prep_w<<<(N_DEL * N_NEUR * N_NEUR) / 256, 256, 0, stream>>>(w, signs, dmap, W);
    transpose_inp<<<T_STEPS, 256, 0, stream>>>(inputs, inpT);

    for (int t = 0; t < T_STEPS; ++t) {
        float* pw       = (t & 1) ? part1 : part0;
        const float* pr = (t & 1) ? part0 : part1;   // partials of step t-1
        fused_step<<<1088, 256, 0, stream>>>(t, W, delays, inpT, w_in, p,
                                             histc, mem, wp, spk, pw, pr);
    }
    // final pointwise for t = 499 (its partials are in part[499&1] = part1)
    tail_pointwise<<<64, 256, 0, stream>>>(part1, inpT, w_in, p,
                                           mem, wp, histc, spk);

    h2_gemm<<<T_STEPS, 256, 0, stream>>>(spk, w_out, h2);
    out_scan<<<8, 256, 0, stream>>>(h2, out);
}

// Round 4
// 36969.461 us; speedup vs baseline: 1.0269x; 1.0269x over previous
//
#include <hip/hip_runtime.h>
#include <stdint.h>

#define N_NEUR  1024
#define N_INP   256
#define N_OUTC  32
#define T_STEPS 500
#define BATCH   64
#define N_DEL   8
#define NB      (N_NEUR*BATCH)     // 65536 (n,b) elements, b fastest
#define HSLOTS  130                // circular history depth (reads are ages 2..129)
#define NPART   32                 // split-K partials per element

// ---------------------------------------------------------------------------
// W_eff[d][e][o] = dmap[d][e][o] * sign[e] * |w[e][o]|
__global__ __launch_bounds__(256) void prep_w(const float* __restrict__ w,
                                              const float* __restrict__ signs,
                                              const float* __restrict__ dmap,
                                              float* __restrict__ W) {
    size_t i = (size_t)blockIdx.x * 256 + threadIdx.x;   // < 8*1024*1024
    int r = (int)(i & (size_t)(N_NEUR * N_NEUR - 1));    // (e,o) flat
    int e = r >> 10;
    W[i] = dmap[i] * signs[e] * fabsf(w[r]);
}

// ---------------------------------------------------------------------------
// inpT[t][c][b] = inputs[b][t][c]   (LDS-tiled transpose, both sides coalesced)
__global__ __launch_bounds__(256) void transpose_inp(const float* __restrict__ inp,
                                                     float* __restrict__ inpT) {
    __shared__ float L[N_INP * 64];          // [c][b], XOR-swizzled
    int t = blockIdx.x;
    int tid = threadIdx.x;                   // = c on the read side
    for (int b = 0; b < 64; ++b) {
        float v = inp[((size_t)b * T_STEPS + t) * N_INP + tid];  // coalesced over c
        L[tid * 64 + (b ^ (tid & 63))] = v;
    }
    __syncthreads();
    int lane = tid & 63;
    int wv   = tid >> 6;
    for (int cc = 0; cc < 64; ++cc) {
        int c = cc * 4 + wv;
        inpT[((size_t)t * N_INP + c) * 64 + lane] = L[c * 64 + (lane ^ (c & 63))];
    }
}

// ---------------------------------------------------------------------------
// Pointwise update of step s, one wave: n in [n0, n0+4), lanes = batch.
// Computes h1 on the fly, reduces NPART split-K partials, updates mem/w_p,
// writes hist circular slot and packed spike bits.
__device__ __forceinline__ void pointwise_wave(int s, int n0, int lane,
        const float* __restrict__ part, const float* __restrict__ inpT,
        const float* __restrict__ w_in, const float* __restrict__ p,
        float* __restrict__ mem, float* __restrict__ wp_arr,
        float* __restrict__ histc, unsigned long long* __restrict__ spk) {
    float h1v[4] = {0.f, 0.f, 0.f, 0.f};
    const float* irow = inpT + (size_t)s * (N_INP * 64) + lane;
    const float4* wcol = (const float4*)(w_in + n0);   // uniform -> s_load_dwordx4
#pragma unroll 4
    for (int c = 0; c < N_INP; ++c) {
        float a = irow[(size_t)c * 64];                // coalesced vload
        float4 wq = wcol[(size_t)c * (N_NEUR / 4)];
        h1v[0] = fmaf(a, wq.x, h1v[0]);
        h1v[1] = fmaf(a, wq.y, h1v[1]);
        h1v[2] = fmaf(a, wq.z, h1v[2]);
        h1v[3] = fmaf(a, wq.w, h1v[3]);
    }
    int slot = s % HSLOTS;
#pragma unroll
    for (int r = 0; r < 4; ++r) {
        int n = n0 + r;
        int i = n * 64 + lane;
        float syn = 0.f;
#pragma unroll 8
        for (int kc = 0; kc < NPART; ++kc) syn += part[(size_t)kc * NB + i];
        float m = mem[i];
        float w = wp_arr[i];
        float out = (m - 1.0f > 0.0f) ? 1.0f : 0.0f;
        float pn = p[n];
        float pd = (pn < 0.0f) ? 1.0f : 0.0f;
        w = w * 0.95f + out * pn * (1.0f + pd * w);
        wp_arr[i] = w;
        histc[(size_t)slot * NB + i] = out * (1.0f + w);   // >0 iff spike
        mem[i] = 0.9f * m + h1v[r] + syn - out;
        unsigned long long mask = __ballot(out > 0.0f);
        if (lane == 0) spk[(size_t)s * N_NEUR + n] = mask;
    }
}

// ---------------------------------------------------------------------------
// One simulation step, single launch, grid = 2176 blocks x 128 (2 waves):
//  - blocks [0,128): pointwise update of step t-1 (2 waves x 4 n = 8 n/block).
//    Writes hist slot (t-1)%HSLOTS, mem, w_p, spk -- nothing step-t's GEMM
//    reads (min delay 1 -> GEMM reads slots of age >= 2). Dispatched first so
//    they run concurrently with the GEMM blocks.
//  - blocks [128, 128+2048): split-K GEMM. Block = (ot, kcg); wave wv takes
//    kc = kcg*2+wv in [0,64): d = kc&7, e-chunk (kc>>3)*128. LDS-reduce the
//    two waves -> partial[kcg][n][b].
//      syn_p[b][o] = sum_d sum_e hist[slot(t-1-delay_d)][e][b] * W[d][e][o]
//    delays[d] goes through readfirstlane so slot/weight addresses are SGPRs
//    -> weight reads are s_load_dwordx4 (scalar pipe), hist read is the only
//    per-lane VMEM in the inner loop.
__global__ __launch_bounds__(128) void fused_step(int t,
        const float* __restrict__ W, const int* __restrict__ delays,
        const float* __restrict__ inpT, const float* __restrict__ w_in,
        const float* __restrict__ p,
        float* __restrict__ histc, float* __restrict__ mem,
        float* __restrict__ wp_arr, unsigned long long* __restrict__ spk,
        float* __restrict__ part_w, const float* __restrict__ part_r) {
    __shared__ float R[16 * 64];   // 4 KB: wave-1 accumulators for the reduce
    int bx = blockIdx.x;
    int tid = threadIdx.x;
    int lane = tid & 63;
    int wv   = tid >> 6;
    if (bx < 128) {
        if (t > 0)
            pointwise_wave(t - 1, bx * 8 + wv * 4, lane, part_r, inpT, w_in,
                           p, mem, wp_arr, histc, spk);
        return;
    }
    int gx  = bx - 128;
    int ot  = gx & 63;                 // o-tile of 16; XCD = ot%8 -> W L2-partitioned
    int kcg = gx >> 6;                 // [0,32) partial group
    int kc  = kcg * 2 + wv;            // [0,64) k-chunk
    int d   = kc & 7;
    int e0  = (kc >> 3) << 7;          // e-chunk of 128
    int dl  = __builtin_amdgcn_readfirstlane(delays[d]);  // -> SGPR (uniformity!)
    int tau = t - 1 - dl;
    float acc[16];
#pragma unroll
    for (int j = 0; j < 16; ++j) acc[j] = 0.f;
    if (tau >= 0) {                    // tau<0: reference reads zero history
        int slot = tau % HSLOTS;
        const float* hrow  = histc + (size_t)slot * NB + (size_t)e0 * 64 + lane;
        const float* wbase = W + ((size_t)d * N_NEUR + e0) * N_NEUR + ot * 16;
#pragma unroll 4
        for (int e = 0; e < 128; ++e) {
            float a = hrow[(size_t)e * 64];                 // coalesced vload
            const float4* w4 = (const float4*)(wbase + (size_t)e * N_NEUR); // SGPR
            float4 w0 = w4[0], w1 = w4[1], w2 = w4[2], w3 = w4[3];
            acc[0]  = fmaf(a, w0.x, acc[0]);  acc[1]  = fmaf(a, w0.y, acc[1]);
            acc[2]  = fmaf(a, w0.z, acc[2]);  acc[3]  = fmaf(a, w0.w, acc[3]);
            acc[4]  = fmaf(a, w1.x, acc[4]);  acc[5]  = fmaf(a, w1.y, acc[5]);
            acc[6]  = fmaf(a, w1.z, acc[6]);  acc[7]  = fmaf(a, w1.w, acc[7]);
            acc[8]  = fmaf(a, w2.x, acc[8]);  acc[9]  = fmaf(a, w2.y, acc[9]);
            acc[10] = fmaf(a, w2.z, acc[10]); acc[11] = fmaf(a, w2.w, acc[11]);
            acc[12] = fmaf(a, w3.x, acc[12]); acc[13] = fmaf(a, w3.y, acc[13]);
            acc[14] = fmaf(a, w3.z, acc[14]); acc[15] = fmaf(a, w3.w, acc[15]);
        }
    }
    if (wv == 1) {
#pragma unroll
        for (int j = 0; j < 16; ++j) R[j * 64 + lane] = acc[j];
    }
    __syncthreads();
    if (wv == 0) {
        float* pw = part_w + (size_t)kcg * NB + (size_t)(ot * 16) * 64 + lane;
#pragma unroll
        for (int j = 0; j < 16; ++j) pw[(size_t)j * 64] = acc[j] + R[j * 64 + lane];
    }
}

// ---------------------------------------------------------------------------
__global__ __launch_bounds__(128) void tail_pointwise(
        const float* __restrict__ part, const float* __restrict__ inpT,
        const float* __restrict__ w_in, const float* __restrict__ p,
        float* __restrict__ mem, float* __restrict__ wp_arr,
        float* __restrict__ histc, unsigned long long* __restrict__ spk) {
    int lane = threadIdx.x & 63;
    int wv   = threadIdx.x >> 6;
    pointwise_wave(T_STEPS - 1, blockIdx.x * 8 + wv * 4, lane, part, inpT,
                   w_in, p, mem, wp_arr, histc, spk);
}

// ---------------------------------------------------------------------------
// h2[t][b][o] = sum_n spk_bit(t,n,b) * w_out[n][o]
__global__ __launch_bounds__(256) void h2_gemm(const unsigned long long* __restrict__ spk,
                                               const float* __restrict__ w_out,
                                               float* __restrict__ h2) {
    int t = blockIdx.x;
    int lane = threadIdx.x & 63;     // = b
    int wv   = threadIdx.x >> 6;
    int o0 = wv * 8;
    float acc[8];
#pragma unroll
    for (int j = 0; j < 8; ++j) acc[j] = 0.f;
    for (int n = 0; n < N_NEUR; ++n) {
        unsigned long long mask = spk[(size_t)t * N_NEUR + n];   // uniform
        float s = (float)((mask >> lane) & 1ULL);
        const float* wr = w_out + n * N_OUTC + o0;               // uniform
#pragma unroll
        for (int j = 0; j < 8; ++j) acc[j] = fmaf(s, wr[j], acc[j]);
    }
#pragma unroll
    for (int j = 0; j < 8; ++j)
        h2[((size_t)t * BATCH + lane) * N_OUTC + o0 + j] = acc[j];
}

// ---------------------------------------------------------------------------
// out[b][t][o] : leaky-integrator scan over h2
__global__ __launch_bounds__(256) void out_scan(const float* __restrict__ h2,
                                                float* __restrict__ out) {
    int tid = blockIdx.x * 256 + threadIdx.x;   // 2048 = 64b * 32o
    int o = tid & 31;
    int b = tid >> 5;
    float acc = 0.f;
    for (int t = 0; t < T_STEPS; ++t) {
        acc = 0.9f * acc + h2[((size_t)t * BATCH + b) * N_OUTC + o];
        out[((size_t)b * T_STEPS + t) * N_OUTC + o] = acc;
    }
}

// ---------------------------------------------------------------------------
extern "C" void kernel_launch(void* const* d_in, const int* in_sizes, int n_in,
                              void* d_out, int out_size, void* d_ws, size_t ws_size,
                              hipStream_t stream) {
    (void)in_sizes; (void)n_in; (void)out_size; (void)ws_size;
    const float* inputs = (const float*)d_in[0];
    const float* w      = (const float*)d_in[1];
    const float* w_in   = (const float*)d_in[2];
    const float* w_out  = (const float*)d_in[3];
    const float* signs  = (const float*)d_in[4];
    const float* p      = (const float*)d_in[5];
    const float* dmap   = (const float*)d_in[6];
    const int*   delays = (const int*)d_in[7];
    float* out = (float*)d_out;

    // workspace layout: 125,894,656 B = 120.06 MiB (< 120.56 MiB proven OK)
    float* ws    = (float*)d_ws;
    float* W     = ws;                                        //  8,388,608 f
    float* inpT  = W + (size_t)N_DEL * N_NEUR * N_NEUR;       //  8,192,000 f
    float* histc = inpT + (size_t)T_STEPS * N_INP * BATCH;    //  8,519,680 f
    float* part0 = histc + (size_t)HSLOTS * NB;               //  2,097,152 f
    float* part1 = part0 + (size_t)NPART * NB;                //  2,097,152 f
    float* mem   = part1 + (size_t)NPART * NB;                //     65,536 f
    float* wp    = mem + NB;                                  //     65,536 f
    float* h2    = wp + NB;                                   //  1,024,000 f
    unsigned long long* spk = (unsigned long long*)(h2 + (size_t)T_STEPS * BATCH * N_OUTC);

    // zero-init: circular history (wrapped reads must see 0), mem+wp (adjacent)
    hipMemsetAsync(histc, 0, (size_t)HSLOTS * NB * sizeof(float), stream);
    hipMemsetAsync(mem, 0, (size_t)2 * NB * sizeof(float), stream);

    prep_w<<<(N_DEL * N_NEUR * N_NEUR) / 256, 256, 0, stream>>>(w, signs, dmap, W);
    transpose_inp<<<T_STEPS, 256, 0, stream>>>(inputs, inpT);

    for (int t = 0; t < T_STEPS; ++t) {
        float* pw       = (t & 1) ? part1 : part0;
        const float* pr = (t & 1) ? part0 : part1;   // partials of step t-1
        fused_step<<<128 + 2048, 128, 0, stream>>>(t, W, delays, inpT, w_in, p,
                                                   histc, mem, wp, spk, pw, pr);
    }
    // final pointwise for t = 499 (its partials are in part[499&1] = part1)
    tail_pointwise<<<128, 128, 0, stream>>>(part1, inpT, w_in, p,
                                            mem, wp, histc, spk);

    h2_gemm<<<T_STEPS, 256, 0, stream>>>(spk, w_out, h2);
    out_scan<<<8, 256, 0, stream>>>(h2, out);
}